// Round 6
// baseline (110.019 us; speedup 1.0000x reference)
//
#include <hip/hip_runtime.h>
#include <hip/hip_bf16.h>
#include <math.h>

// Problem constants (from reference): path_fea (131072, 64, 1, 1, 2) fp32
#define B_ROWS   131072
#define D_DIM    128          // 64 * 2
#define P_SAMP   16
#define G_GROUPS 8192         // B / P
#define K1_BLOCKS (G_GROUPS / 4)

// K2 tiling: 64x64 block tiles over the triangle, 32x32 per wave.
#define T64      128          // 64-row tiles per dim (G / 64)
#define NTRI64   8256         // T64*(T64+1)/2 triangular block-tiles
#define NCELLS   32           // done-counter fan-in (8256 = 32 * 258)
#define CELL_Q   (NTRI64 / NCELLS)   // 258 blocks per cell

// Exact prescreen: sum over first 32 dims of (ci-cj)^2 is a LOWER bound on
// d2_full (non-negative terms), so d2_sub >= SCREEN_T  =>  hinge == 0.
// bf16 rounding error on the gram is < ~0.02 here, far inside the 0.25
// margin (threshold 1.25 vs exact-need 1.0). Survivors get an exact fp32
// recompute, so screen false-positives only cost time, never error.
#define SCREEN_T 1.25f

typedef __bf16 bf16x8  __attribute__((ext_vector_type(8)));
typedef float  floatx4 __attribute__((ext_vector_type(4)));
typedef unsigned short u16x8 __attribute__((ext_vector_type(8)));

// K=32 fragment-ordered center layout (written by K1, read by K2):
//   granule index = (row>>4)*64 + gg*16 + (row&15),  gg = k-octet 0..3
//   each granule = 8 bf16 (16 B). A 16-row panel = 64 contiguous granules
//   -> every wave fragment load is 1 KB contiguous (L2-resident, 512 KB).

__device__ __forceinline__ float wave_red64(float v) {
    #pragma unroll
    for (int off = 32; off > 0; off >>= 1) v += __shfl_xor(v, off, 64);
    return v;
}

// sum over the 16-lane row via DPP row_ror rotations (VALU pipe, no DS)
template <int CTRL>
__device__ __forceinline__ float dpp_ror_add(float v) {
    int r = __builtin_amdgcn_update_dpp(0, __builtin_bit_cast(int, v),
                                        CTRL, 0xf, 0xf, false);
    return v + __builtin_bit_cast(float, r);
}
__device__ __forceinline__ float row16_sum(float v) {
    v = dpp_ror_add<0x121>(v);   // row_ror:1
    v = dpp_ror_add<0x122>(v);   // row_ror:2
    v = dpp_ror_add<0x124>(v);   // row_ror:4
    v = dpp_ror_add<0x128>(v);   // row_ror:8
    return v;
}

// ---------------------------------------------------------------------------
// K1: per-group centers + intra hinge. (Unchanged from R5 — passing.)
// Outputs: fp32 centers [G][128] (for exact survivor recompute), bf16 K=32
// fragment granules (screen operands), sq32[g] = |center[0:32]|^2, intra
// partials. One wave per group; all global loads 1KB-contiguous wave-loads.
// Block 0 also re-initializes the accumulator + done-counter cells.
// ---------------------------------------------------------------------------
__global__ __launch_bounds__(256) void k_center_intra(
    const float* __restrict__ x,            // [B, 128]
    uint2* __restrict__ cfrag,               // K=32 granule halves (8B each)
    float* __restrict__ centerf,             // [G, 128] fp32 centers
    float* __restrict__ sq32,                // [G] norm^2 over dims 0..31
    float* __restrict__ partial,             // [K1_BLOCKS] intra partials
    float* __restrict__ acc,                 // acc[0] zeroed here
    unsigned int* __restrict__ cells,        // NCELLS counters, 128B apart
    unsigned int* __restrict__ root)         // root counter
{
    const int wave = threadIdx.x >> 6;
    const int lane = threadIdx.x & 63;
    const int half = lane >> 5;      // sample parity this lane owns
    const int c    = lane & 31;      // dim-quad index (4 dims per lane)
    const int g    = blockIdx.x * 4 + wave;

    if (blockIdx.x == 0) {
        if (threadIdx.x < NCELLS) cells[threadIdx.x * 32] = 0u;
        else if (threadIdx.x == NCELLS) { acc[0] = 0.f; root[0] = 0u; }
    }

    // sample s = 2*l + half, dims 4c..4c+3
    const float* base = x + (size_t)g * (P_SAMP * D_DIM) + half * D_DIM + c * 4;

    floatx4 v[8];
    #pragma unroll
    for (int l = 0; l < 8; ++l)
        v[l] = *(const floatx4*)(base + l * (2 * D_DIM));

    floatx4 cs = v[0];
    #pragma unroll
    for (int l = 1; l < 8; ++l) cs += v[l];
    #pragma unroll
    for (int k = 0; k < 4; ++k) cs[k] += __shfl_xor(cs[k], 32, 64);
    floatx4 ctr = cs * (1.0f / P_SAMP);

    // 8 parallel partial sums: per-sample dist^2
    float p[8];
    #pragma unroll
    for (int l = 0; l < 8; ++l) {
        floatx4 d = v[l] - ctr;
        p[l] = d[0]*d[0] + d[1]*d[1] + d[2]*d[2] + d[3]*d[3];
    }
    #pragma unroll
    for (int s = 0; s < 8; ++s) {
        p[s] = row16_sum(p[s]);
        p[s] += __shfl_xor(p[s], 16, 64);
    }
    // p[l] = full 128-dim dist^2 of sample 2l+half

    // sq32: lanes c=0..7 hold dims 0..31; reduce within 8-lane groups
    float s32 = ctr[0]*ctr[0] + ctr[1]*ctr[1] + ctr[2]*ctr[2] + ctr[3]*ctr[3];
    s32 += __shfl_xor(s32, 1, 64);
    s32 += __shfl_xor(s32, 2, 64);
    s32 += __shfl_xor(s32, 4, 64);
    if (lane == 0) sq32[g] = s32;

    if (half == 0) {
        // fp32 center: 512 B contiguous per wave
        *(floatx4*)(centerf + (size_t)g * D_DIM + c * 4) = ctr;
        // bf16 K=32 fragment granules (dims 0..31 only)
        if (c < 8) {
            unsigned int b0 = __builtin_bit_cast(unsigned short, (__bf16)ctr[0]);
            unsigned int b1 = __builtin_bit_cast(unsigned short, (__bf16)ctr[1]);
            unsigned int b2 = __builtin_bit_cast(unsigned short, (__bf16)ctr[2]);
            unsigned int b3 = __builtin_bit_cast(unsigned short, (__bf16)ctr[3]);
            uint2 pk;
            pk.x = (b1 << 16) | b0;
            pk.y = (b3 << 16) | b2;
            const int gran = (g >> 4) * 64 + (c >> 1) * 16 + (g & 15);
            cfrag[gran * 2 + (c & 1)] = pk;
        }
    }

    float isum = 0.f;
    #pragma unroll
    for (int l = 0; l < 8; ++l) {
        float d = sqrtf(p[l]);
        float t = fmaxf(d - 0.1f, 0.f);
        isum += t * t;
    }
    isum += __shfl_xor(isum, 32, 64);

    __shared__ float sh[4];
    if (lane == 0) sh[wave] = isum;
    __syncthreads();
    if (threadIdx.x == 0)
        partial[blockIdx.x] = sh[0] + sh[1] + sh[2] + sh[3];
}

// ---------------------------------------------------------------------------
// K2: screen + exact survivor hinge + finalize, fused. One block per 64x64
// triangular tile (8256 blocks); 4 waves = 32x32 quadrants.
//
// R5 post-mortem: the 64x64-per-wave version held ~128 unified VGPR+AGPR
// (c4[4][4]=64 acc) -> 4 waves/SIMD -> K2 ~22 us vs ~8 us floor. This
// version holds aa[2]+bb[2]+c4[2][2] ~= 60 regs -> 8 waves/SIMD.
//
// Hot path: 4 MFMAs + 16 fma + 16 min per lane -> per-lane dmin. Survivor
// handling (essentially never on this data) sits behind a wave-uniform
// __ballot gate: rebuild a 16-bit mask with compile-time indices (keeps c4
// in registers, R3 lesson), ctz-walk, exact fp32 recompute from centerf.
// Finalize: two-level done counter (32 cells x 258, 128 B apart) -- longest
// same-address atomic chain 258, cells in parallel (R4 lesson).
// ---------------------------------------------------------------------------
__global__ __launch_bounds__(256) void k_screen_final(
    const u16x8* __restrict__ cfrag,         // K=32 granule array (16 B each)
    const float* __restrict__ sq32,          // [G]
    const float* __restrict__ centerf,       // [G, 128] fp32
    const float* __restrict__ partial,       // [K1_BLOCKS] intra partials
    float* __restrict__ acc,                 // inter hinge accumulator
    unsigned int* __restrict__ cells,        // NCELLS counters, 128B apart
    unsigned int* __restrict__ root,         // root counter
    float* __restrict__ out)                 // out[0]=inter, out[1]=intra
{
    // triangular decode over T64=128: off(i) = 128i - i(i-1)/2
    const int bid = blockIdx.x;
    float sf = sqrtf(128.5f * 128.5f - 2.0f * (float)bid);
    int ti = (int)(128.5f - sf);
    if (ti < 0) ti = 0;
    if (ti > T64 - 1) ti = T64 - 1;
    #define TRI_OFF(i) ((i) * T64 - (((i) * ((i) - 1)) >> 1))
    while (ti > 0 && TRI_OFF(ti) > bid) --ti;
    while (ti < T64 - 1 && TRI_OFF(ti + 1) <= bid) ++ti;
    const int tj = ti + (bid - TRI_OFF(ti));
    #undef TRI_OFF

    const int t    = threadIdx.x;
    const int wave = t >> 6;
    const int lane = t & 63;
    const int wr   = wave >> 1;    // 0..1: which 32-row half of i
    const int wc   = wave & 1;     // 0..1: which 32-col half of j
    const int lrow = lane & 15;
    const int quad = lane >> 4;

    const int i0 = ti * 64 + wr * 32;
    const int j0 = tj * 64 + wc * 32;

    const bool bdiag = (ti == tj);
    const bool skipq = (bdiag && wr > wc);   // strictly-lower quadrant (i>j)
    const bool qdiag = (bdiag && wr == wc);

    float hsum = 0.f;
    if (!skipq) {
        // fragment loads: 4 x 1 KB contiguous wave-loads, all L2/IC-hot
        bf16x8 aa[2], bb[2];
        #pragma unroll
        for (int nt = 0; nt < 2; ++nt)
            bb[nt] = __builtin_bit_cast(bf16x8,
                       cfrag[(size_t)((j0 >> 4) + nt) * 64 + quad * 16 + lrow]);
        #pragma unroll
        for (int mt = 0; mt < 2; ++mt)
            aa[mt] = __builtin_bit_cast(bf16x8,
                       cfrag[(size_t)((i0 >> 4) + mt) * 64 + quad * 16 + lrow]);

        floatx4 sqi[2];
        float   sqj[2];
        #pragma unroll
        for (int mt = 0; mt < 2; ++mt)
            sqi[mt] = *(const floatx4*)(sq32 + i0 + mt * 16 + quad * 4);
        #pragma unroll
        for (int nt = 0; nt < 2; ++nt)
            sqj[nt] = sq32[j0 + nt * 16 + lrow];

        floatx4 c4[2][2] = {};   // 4 accumulator tiles, single K=32 step
        #pragma unroll
        for (int mt = 0; mt < 2; ++mt)
            #pragma unroll
            for (int nt = 0; nt < 2; ++nt)
                c4[mt][nt] = __builtin_amdgcn_mfma_f32_16x16x32_bf16(
                                aa[mt], bb[nt], c4[mt][nt], 0, 0, 0);

        // hot path: 16 fma + 16 min -> per-lane dmin (indices compile-time)
        float dmin = 1e30f;
        #pragma unroll
        for (int mt = 0; mt < 2; ++mt) {
            #pragma unroll
            for (int nt = 0; nt < 2; ++nt) {
                const int ib = i0 + mt * 16 + quad * 4;
                const int j  = j0 + nt * 16 + lrow;
                #pragma unroll
                for (int r = 0; r < 4; ++r) {
                    float d2s = fmaf(-2.0f, c4[mt][nt][r],
                                     sqi[mt][r] + sqj[nt]);
                    d2s = (qdiag && (j <= ib + r)) ? 1e30f : d2s;
                    dmin = fminf(dmin, d2s);
                }
            }
        }

        // survivor path: wave-rare; rebuild mask with compile-time indices
        if (__ballot(dmin < SCREEN_T)) {
            unsigned int m = 0u;
            #pragma unroll
            for (int mt = 0; mt < 2; ++mt) {
                #pragma unroll
                for (int nt = 0; nt < 2; ++nt) {
                    const int ib = i0 + mt * 16 + quad * 4;
                    const int j  = j0 + nt * 16 + lrow;
                    #pragma unroll
                    for (int r = 0; r < 4; ++r) {
                        float d2s = fmaf(-2.0f, c4[mt][nt][r],
                                         sqi[mt][r] + sqj[nt]);
                        d2s = (qdiag && (j <= ib + r)) ? 1e30f : d2s;
                        m |= (unsigned int)(d2s < SCREEN_T)
                             << (mt * 8 + nt * 4 + r);
                    }
                }
            }
            while (m) {                      // exact fp32 recompute
                const int b = (int)__builtin_ctz(m);
                m &= m - 1;
                const int mt = b >> 3;
                const int nt = (b >> 2) & 1;
                const int r  = b & 3;
                const int i  = i0 + mt * 16 + quad * 4 + r;
                const int j  = j0 + nt * 16 + lrow;
                const float* ci = centerf + (size_t)i * D_DIM;
                const float* cj = centerf + (size_t)j * D_DIM;
                float d2 = 0.f;
                #pragma unroll 4
                for (int k = 0; k < D_DIM; k += 4) {
                    floatx4 a4 = *(const floatx4*)(ci + k);
                    floatx4 b4 = *(const floatx4*)(cj + k);
                    floatx4 df = a4 - b4;
                    d2 += df[0]*df[0] + df[1]*df[1] + df[2]*df[2] + df[3]*df[3];
                }
                float d  = sqrtf(d2);
                float tt = fmaxf(1.0f - d, 0.f);
                hsum += tt * tt;
            }
        }
    }

    // block reduction -> (rare) publish -> two-level done counter
    __shared__ float sh[4];
    __shared__ int isLast;
    hsum = wave_red64(hsum);
    if (lane == 0) sh[wave] = hsum;
    __syncthreads();
    if (t == 0) {
        float bh = sh[0] + sh[1] + sh[2] + sh[3];
        if (bh != 0.f) {                     // rare: publish + fence
            atomicAdd(acc, bh);
            __threadfence();
        }
        isLast = 0;
        unsigned int old = atomicAdd(&cells[(bid & (NCELLS - 1)) * 32], 1u);
        if (old == CELL_Q - 1) {             // this cell complete
            unsigned int r = atomicAdd(root, 1u);
            if (r == NCELLS - 1) isLast = 1; // all cells complete
        }
    }
    __syncthreads();
    if (isLast) {
        // whole block cooperates: sum ALL K1_BLOCKS (=2048) intra partials
        float s = 0.f;
        #pragma unroll
        for (int i = 0; i < K1_BLOCKS / 256; ++i)
            s += partial[t + i * 256];
        s = wave_red64(s);
        if (lane == 0) sh[wave] = s;
        __syncthreads();
        if (t == 0) {
            __threadfence();
            float inter = atomicAdd(acc, 0.0f);  // coherent read
            const float n_pairs = (float)G_GROUPS * (float)(G_GROUPS - 1) * 0.5f;
            out[0] = inter / n_pairs;
            out[1] = (sh[0] + sh[1] + sh[2] + sh[3]) / (float)B_ROWS;
        }
    }
}

extern "C" void kernel_launch(void* const* d_in, const int* in_sizes, int n_in,
                              void* d_out, int out_size, void* d_ws, size_t ws_size,
                              hipStream_t stream) {
    const float* x = (const float*)d_in[0];
    float* out = (float*)d_out;

    // workspace layout
    float*        acc     = (float*)d_ws;                              // 4 B
    unsigned int* root    = (unsigned int*)((char*)d_ws + 64);         // 4 B
    unsigned int* cells   = (unsigned int*)((char*)d_ws + 128);        // 4 KB (32 x 128B)
    float*        partial = (float*)((char*)d_ws + 8192);              // 8 KB
    float*        sq32    = (float*)((char*)d_ws + 16384);             // 32 KB
    uint2*        cfrag   = (uint2*)((char*)d_ws + 65536);             // 512 KB
    float*        centerf = (float*)((char*)d_ws + (1u << 20));        // 4 MB

    k_center_intra<<<K1_BLOCKS, 256, 0, stream>>>(x, cfrag, centerf, sq32,
                                                  partial, acc, cells, root);

    k_screen_final<<<NTRI64, 256, 0, stream>>>((const u16x8*)cfrag, sq32,
                                               centerf, partial, acc, cells,
                                               root, out);
}

// Round 7
// 106.530 us; speedup vs baseline: 1.0328x; 1.0328x over previous
//
#include <hip/hip_runtime.h>
#include <hip/hip_bf16.h>
#include <math.h>

// Problem constants (from reference): path_fea (131072, 64, 1, 1, 2) fp32
#define B_ROWS   131072
#define D_DIM    128          // 64 * 2
#define P_SAMP   16
#define G_GROUPS 8192         // B / P
#define T128     64           // 128-row tiles per dim (G / 128)
#define NTRI2    2080         // T128*(T128+1)/2 triangular block-tiles
#define K1_BLOCKS (G_GROUPS / 4)
#define NCELLS   32           // done-counter fan-in (2080 = 32 * 65)
#define CELL_Q   (NTRI2 / NCELLS)   // 65 blocks per cell

// Exact prescreen: sum over first 32 dims of (ci-cj)^2 is a LOWER bound on
// d2_full (non-negative terms), so d2_sub >= SCREEN_T  =>  hinge == 0.
// bf16 rounding error on the gram is < ~0.02 here, far inside the 0.25
// margin (threshold 1.25 vs exact-need 1.0). Survivors get an exact fp32
// recompute, so screen false-positives only cost time, never error.
#define SCREEN_T 1.25f

typedef __bf16 bf16x8  __attribute__((ext_vector_type(8)));
typedef float  floatx4 __attribute__((ext_vector_type(4)));
typedef unsigned short u16x8 __attribute__((ext_vector_type(8)));

// K=32 fragment-ordered center layout (written by K1, read by K2):
//   granule index = (row>>4)*64 + gg*16 + (row&15),  gg = k-octet 0..3
//   each granule = 8 bf16 (16 B). A 16-row panel = 64 contiguous granules
//   -> every wave fragment load is 1 KB contiguous (L2-resident, 512 KB).

__device__ __forceinline__ float wave_red64(float v) {
    #pragma unroll
    for (int off = 32; off > 0; off >>= 1) v += __shfl_xor(v, off, 64);
    return v;
}

// sum over the 16-lane row via DPP row_ror rotations (VALU pipe, no DS)
template <int CTRL>
__device__ __forceinline__ float dpp_ror_add(float v) {
    int r = __builtin_amdgcn_update_dpp(0, __builtin_bit_cast(int, v),
                                        CTRL, 0xf, 0xf, false);
    return v + __builtin_bit_cast(float, r);
}
__device__ __forceinline__ float row16_sum(float v) {
    v = dpp_ror_add<0x121>(v);   // row_ror:1
    v = dpp_ror_add<0x122>(v);   // row_ror:2
    v = dpp_ror_add<0x124>(v);   // row_ror:4
    v = dpp_ror_add<0x128>(v);   // row_ror:8
    return v;
}

// ---------------------------------------------------------------------------
// K1: per-group centers + intra hinge.
// Outputs: fp32 centers [G][128] (for exact survivor recompute), bf16 K=32
// fragment granules (screen operands), sq32[g] = |center[0:32]|^2, intra
// partials. One wave per group; all global loads 1KB-contiguous wave-loads.
// Block 0 also re-initializes the accumulator + done-counter cells.
// ---------------------------------------------------------------------------
__global__ __launch_bounds__(256) void k_center_intra(
    const float* __restrict__ x,            // [B, 128]
    uint2* __restrict__ cfrag,               // K=32 granule halves (8B each)
    float* __restrict__ centerf,             // [G, 128] fp32 centers
    float* __restrict__ sq32,                // [G] norm^2 over dims 0..31
    float* __restrict__ partial,             // [K1_BLOCKS] intra partials
    float* __restrict__ acc,                 // acc[0] zeroed here
    unsigned int* __restrict__ cells,        // NCELLS counters, 128B apart
    unsigned int* __restrict__ root)         // root counter
{
    const int wave = threadIdx.x >> 6;
    const int lane = threadIdx.x & 63;
    const int half = lane >> 5;      // sample parity this lane owns
    const int c    = lane & 31;      // dim-quad index (4 dims per lane)
    const int g    = blockIdx.x * 4 + wave;

    if (blockIdx.x == 0) {
        if (threadIdx.x < NCELLS) cells[threadIdx.x * 32] = 0u;
        else if (threadIdx.x == NCELLS) { acc[0] = 0.f; root[0] = 0u; }
    }

    // sample s = 2*l + half, dims 4c..4c+3
    const float* base = x + (size_t)g * (P_SAMP * D_DIM) + half * D_DIM + c * 4;

    floatx4 v[8];
    #pragma unroll
    for (int l = 0; l < 8; ++l)
        v[l] = *(const floatx4*)(base + l * (2 * D_DIM));

    floatx4 cs = v[0];
    #pragma unroll
    for (int l = 1; l < 8; ++l) cs += v[l];
    #pragma unroll
    for (int k = 0; k < 4; ++k) cs[k] += __shfl_xor(cs[k], 32, 64);
    floatx4 ctr = cs * (1.0f / P_SAMP);

    // 8 parallel partial sums: per-sample dist^2
    float p[8];
    #pragma unroll
    for (int l = 0; l < 8; ++l) {
        floatx4 d = v[l] - ctr;
        p[l] = d[0]*d[0] + d[1]*d[1] + d[2]*d[2] + d[3]*d[3];
    }
    #pragma unroll
    for (int s = 0; s < 8; ++s) {
        p[s] = row16_sum(p[s]);
        p[s] += __shfl_xor(p[s], 16, 64);
    }
    // p[l] = full 128-dim dist^2 of sample 2l+half

    // sq32: lanes c=0..7 hold dims 0..31; reduce within 8-lane groups
    float s32 = ctr[0]*ctr[0] + ctr[1]*ctr[1] + ctr[2]*ctr[2] + ctr[3]*ctr[3];
    s32 += __shfl_xor(s32, 1, 64);
    s32 += __shfl_xor(s32, 2, 64);
    s32 += __shfl_xor(s32, 4, 64);
    if (lane == 0) sq32[g] = s32;

    if (half == 0) {
        // fp32 center: 512 B contiguous per wave
        *(floatx4*)(centerf + (size_t)g * D_DIM + c * 4) = ctr;
        // bf16 K=32 fragment granules (dims 0..31 only)
        if (c < 8) {
            unsigned int b0 = __builtin_bit_cast(unsigned short, (__bf16)ctr[0]);
            unsigned int b1 = __builtin_bit_cast(unsigned short, (__bf16)ctr[1]);
            unsigned int b2 = __builtin_bit_cast(unsigned short, (__bf16)ctr[2]);
            unsigned int b3 = __builtin_bit_cast(unsigned short, (__bf16)ctr[3]);
            uint2 pk;
            pk.x = (b1 << 16) | b0;
            pk.y = (b3 << 16) | b2;
            const int gran = (g >> 4) * 64 + (c >> 1) * 16 + (g & 15);
            cfrag[gran * 2 + (c & 1)] = pk;
        }
    }

    float isum = 0.f;
    #pragma unroll
    for (int l = 0; l < 8; ++l) {
        float d = sqrtf(p[l]);
        float t = fmaxf(d - 0.1f, 0.f);
        isum += t * t;
    }
    isum += __shfl_xor(isum, 32, 64);

    __shared__ float sh[4];
    if (lane == 0) sh[wave] = isum;
    __syncthreads();
    if (threadIdx.x == 0)
        partial[blockIdx.x] = sh[0] + sh[1] + sh[2] + sh[3];
}

// ---------------------------------------------------------------------------
// K2: screen + exact survivor hinge + finalize, fused. One block per
// 128x128 triangular tile (2080 blocks); 4 waves = 64x64 quadrants.
// NO LDS staging, NO mid-kernel barrier on the compute path.
// (R6 post-mortem: 32x32/wave tiles at 8256 blocks regressed — K2 is not
// register/occupancy-bound; this 64x64/wave config is the best measured.)
//
// Epilogue is two-phase to keep c4[][] in REGISTERS (R3 post-mortem: any
// runtime index into c4 demotes the whole array to scratch):
//   phase 1 (hot, fully unrolled, branchless): per-lane 64-bit survival
//     bitmask, bit idx = mt*16 + nt*4 + r; all array indices compile-time.
//   phase 2 (cold, rare): ctz-walk the mask, decode (i,j) arithmetically,
//     exact fp32 recompute from centerf. Touches NO register arrays.
//
// Finalize (R4 post-mortem: 2080x {threadfence + same-address atomicAdd}
// serialized at the owning L2 -> ~50 us, every pipe idle):
//   - fence ONLY when publishing a nonzero acc add (rare on this data);
//   - two-level done counter: 32 cells 128 B apart (bid&31 -> exactly 65
//     blocks/cell), cell-completers bump a root counter. Longest
//     same-address chain: 65 atomics instead of 2080.
// ---------------------------------------------------------------------------
__global__ __launch_bounds__(256) void k_screen_final(
    const u16x8* __restrict__ cfrag,         // K=32 granule array (16 B each)
    const float* __restrict__ sq32,          // [G]
    const float* __restrict__ centerf,       // [G, 128] fp32
    const float* __restrict__ partial,       // [K1_BLOCKS] intra partials
    float* __restrict__ acc,                 // inter hinge accumulator
    unsigned int* __restrict__ cells,        // NCELLS counters, 128B apart
    unsigned int* __restrict__ root,         // root counter
    float* __restrict__ out)                 // out[0]=inter, out[1]=intra
{
    // triangular decode over T128=64: off(i) = 64i - i(i-1)/2
    const int bid = blockIdx.x;
    float sf = sqrtf(64.5f * 64.5f - 2.0f * (float)bid);
    int ti = (int)(64.5f - sf);
    if (ti < 0) ti = 0;
    if (ti > T128 - 1) ti = T128 - 1;
    #define TRI_OFF(i) ((i) * T128 - (((i) * ((i) - 1)) >> 1))
    while (ti > 0 && TRI_OFF(ti) > bid) --ti;
    while (ti < T128 - 1 && TRI_OFF(ti + 1) <= bid) ++ti;
    const int tj = ti + (bid - TRI_OFF(ti));
    #undef TRI_OFF

    const int t    = threadIdx.x;
    const int wave = t >> 6;
    const int lane = t & 63;
    const int wr   = wave >> 1;    // 0..1: which 64-row half of i
    const int wc   = wave & 1;     // 0..1: which 64-col half of j
    const int lrow = lane & 15;
    const int quad = lane >> 4;

    const int i0 = ti * 128 + wr * 64;
    const int j0 = tj * 128 + wc * 64;

    const bool bdiag = (ti == tj);
    const bool skipq = (bdiag && wr > wc);   // strictly-lower quadrant (i>j)
    const bool qdiag = (bdiag && wr == wc);

    float hsum = 0.f;
    if (!skipq) {
        // fragment loads: 8 x 1 KB contiguous wave-loads, all L2-hot
        bf16x8 aa[4], bb[4];
        #pragma unroll
        for (int nt = 0; nt < 4; ++nt)
            bb[nt] = __builtin_bit_cast(bf16x8,
                       cfrag[(size_t)((j0 >> 4) + nt) * 64 + quad * 16 + lrow]);
        #pragma unroll
        for (int mt = 0; mt < 4; ++mt)
            aa[mt] = __builtin_bit_cast(bf16x8,
                       cfrag[(size_t)((i0 >> 4) + mt) * 64 + quad * 16 + lrow]);

        floatx4 sqi[4];
        float   sqj[4];
        #pragma unroll
        for (int mt = 0; mt < 4; ++mt)
            sqi[mt] = *(const floatx4*)(sq32 + i0 + mt * 16 + quad * 4);
        #pragma unroll
        for (int nt = 0; nt < 4; ++nt)
            sqj[nt] = sq32[j0 + nt * 16 + lrow];

        floatx4 c4[4][4] = {};   // 16 accumulator tiles, single K=32 step
        #pragma unroll
        for (int mt = 0; mt < 4; ++mt)
            #pragma unroll
            for (int nt = 0; nt < 4; ++nt)
                c4[mt][nt] = __builtin_amdgcn_mfma_f32_16x16x32_bf16(
                                aa[mt], bb[nt], c4[mt][nt], 0, 0, 0);

        // phase 1: branchless survival bitmask (all indices compile-time)
        unsigned long long m = 0ull;
        #pragma unroll
        for (int mt = 0; mt < 4; ++mt) {
            #pragma unroll
            for (int nt = 0; nt < 4; ++nt) {
                const int ib = i0 + mt * 16 + quad * 4;
                const int j  = j0 + nt * 16 + lrow;
                #pragma unroll
                for (int r = 0; r < 4; ++r) {
                    float d2s = sqi[mt][r] + sqj[nt] - 2.0f * c4[mt][nt][r];
                    d2s = (qdiag && (j <= ib + r)) ? 1e30f : d2s;
                    m |= (unsigned long long)(d2s < SCREEN_T)
                         << (mt * 16 + nt * 4 + r);
                }
            }
        }

        // phase 2: rare exact recompute; needs only (i,j), no c4 access
        while (m) {
            const int b = __builtin_ctzll(m);
            m &= m - 1;
            const int mt = b >> 4;
            const int nt = (b >> 2) & 3;
            const int r  = b & 3;
            const int i  = i0 + mt * 16 + quad * 4 + r;
            const int j  = j0 + nt * 16 + lrow;
            const float* ci = centerf + (size_t)i * D_DIM;
            const float* cj = centerf + (size_t)j * D_DIM;
            float d2 = 0.f;
            #pragma unroll 4
            for (int k = 0; k < D_DIM; k += 4) {
                floatx4 a4 = *(const floatx4*)(ci + k);
                floatx4 b4 = *(const floatx4*)(cj + k);
                floatx4 df = a4 - b4;
                d2 += df[0]*df[0] + df[1]*df[1] + df[2]*df[2] + df[3]*df[3];
            }
            float d  = sqrtf(d2);
            float tt = fmaxf(1.0f - d, 0.f);
            hsum += tt * tt;
        }
    }

    // block reduction -> (rare) publish -> two-level done counter
    __shared__ float sh[4];
    __shared__ int isLast;
    hsum = wave_red64(hsum);
    if (lane == 0) sh[wave] = hsum;
    __syncthreads();
    if (t == 0) {
        float bh = sh[0] + sh[1] + sh[2] + sh[3];
        if (bh != 0.f) {                     // rare: publish + fence
            atomicAdd(acc, bh);
            __threadfence();
        }
        isLast = 0;
        unsigned int old = atomicAdd(&cells[(bid & (NCELLS - 1)) * 32], 1u);
        if (old == CELL_Q - 1) {             // this cell complete
            unsigned int r = atomicAdd(root, 1u);
            if (r == NCELLS - 1) isLast = 1; // all cells complete
        }
    }
    __syncthreads();
    if (isLast) {
        // whole block cooperates: sum ALL K1_BLOCKS (=2048) intra partials
        float s = 0.f;
        #pragma unroll
        for (int i = 0; i < K1_BLOCKS / 256; ++i)
            s += partial[t + i * 256];
        s = wave_red64(s);
        if (lane == 0) sh[wave] = s;
        __syncthreads();
        if (t == 0) {
            __threadfence();
            float inter = atomicAdd(acc, 0.0f);  // coherent read
            const float n_pairs = (float)G_GROUPS * (float)(G_GROUPS - 1) * 0.5f;
            out[0] = inter / n_pairs;
            out[1] = (sh[0] + sh[1] + sh[2] + sh[3]) / (float)B_ROWS;
        }
    }
}

extern "C" void kernel_launch(void* const* d_in, const int* in_sizes, int n_in,
                              void* d_out, int out_size, void* d_ws, size_t ws_size,
                              hipStream_t stream) {
    const float* x = (const float*)d_in[0];
    float* out = (float*)d_out;

    // workspace layout
    float*        acc     = (float*)d_ws;                              // 4 B
    unsigned int* root    = (unsigned int*)((char*)d_ws + 64);         // 4 B
    unsigned int* cells   = (unsigned int*)((char*)d_ws + 128);        // 4 KB (32 x 128B)
    float*        partial = (float*)((char*)d_ws + 8192);              // 8 KB
    float*        sq32    = (float*)((char*)d_ws + 16384);             // 32 KB
    uint2*        cfrag   = (uint2*)((char*)d_ws + 65536);             // 512 KB
    float*        centerf = (float*)((char*)d_ws + (1u << 20));        // 4 MB

    k_center_intra<<<K1_BLOCKS, 256, 0, stream>>>(x, cfrag, centerf, sq32,
                                                  partial, acc, cells, root);

    k_screen_final<<<NTRI2, 256, 0, stream>>>((const u16x8*)cfrag, sq32,
                                              centerf, partial, acc, cells,
                                              root, out);
}